// Round 4
// baseline (92.839 us; speedup 1.0000x reference)
//
#include <hip/hip_runtime.h>
#include <stdint.h>

// ---------------------------------------------------------------------------
// RandomParameterizedQuantumConvolutionLayer — single fused kernel.
// N = 524288 rows of 4 angles; 3 fixed random 4-qubit circuits (seed 1024).
// Each 1024-thread block: lanes 0..767 rebuild the 3 folded 16x16 unitaries
// (register state + shfl_xor, fp32 math) into LDS f16 A-fragments (~1.1k cyc,
// ~2.5us total redundancy across 512 blocks); then 16 waves x 64 rows each:
// rr[16] real product vector -> f16 -> LDS -> B-fragments; 6x
// mfma_f32_16x16x32_f16 per 16-row set; epilogue p=re^2+im^2 lane-local,
// signed sums via in-reg butterfly + shfl_xor(16/32); predicated float4 store.
// This removes the tiny serial producer kernel (1 workgroup at idle DVFS
// clocks) and the inter-kernel drain that dominated rounds 0-3.
// ---------------------------------------------------------------------------

namespace {

typedef _Float16 half8 __attribute__((ext_vector_type(8)));
typedef float float4v __attribute__((ext_vector_type(4)));

struct GateList {
  int ty[45];   // 0..6 single (rx,ry,rz,s,t,p,u3); 10..19 double
  int q0[45];
  int q1[45];
  int off[45];  // param offset
};

// ---- CPython-compatible MT19937 (random.Random) ----
struct PyRandom {
  uint32_t mt[624];
  int mti;
  void init_genrand(uint32_t s) {
    mt[0] = s;
    for (int i = 1; i < 624; ++i)
      mt[i] = 1812433253u * (mt[i - 1] ^ (mt[i - 1] >> 30)) + (uint32_t)i;
    mti = 624;
  }
  void init_by_array(const uint32_t* key, int klen) {
    init_genrand(19650218u);
    int i = 1, j = 0;
    int k = 624 > klen ? 624 : klen;
    for (; k; --k) {
      mt[i] = (mt[i] ^ ((mt[i - 1] ^ (mt[i - 1] >> 30)) * 1664525u)) + key[j] + (uint32_t)j;
      ++i; ++j;
      if (i >= 624) { mt[0] = mt[623]; i = 1; }
      if (j >= klen) j = 0;
    }
    for (k = 623; k; --k) {
      mt[i] = (mt[i] ^ ((mt[i - 1] ^ (mt[i - 1] >> 30)) * 1566083941u)) - (uint32_t)i;
      ++i;
      if (i >= 624) { mt[0] = mt[623]; i = 1; }
    }
    mt[0] = 0x80000000u;
    mti = 624;
  }
  uint32_t genrand() {
    if (mti >= 624) {
      const uint32_t mag[2] = {0u, 0x9908b0dfu};
      int kk; uint32_t y;
      for (kk = 0; kk < 227; ++kk) {
        y = (mt[kk] & 0x80000000u) | (mt[kk + 1] & 0x7fffffffu);
        mt[kk] = mt[kk + 397] ^ (y >> 1) ^ mag[y & 1];
      }
      for (; kk < 623; ++kk) {
        y = (mt[kk] & 0x80000000u) | (mt[kk + 1] & 0x7fffffffu);
        mt[kk] = mt[kk - 227] ^ (y >> 1) ^ mag[y & 1];
      }
      y = (mt[623] & 0x80000000u) | (mt[0] & 0x7fffffffu);
      mt[623] = mt[396] ^ (y >> 1) ^ mag[y & 1];
      mti = 0;
    }
    uint32_t y = mt[mti++];
    y ^= y >> 11;
    y ^= (y << 7) & 0x9d2c5680u;
    y ^= (y << 15) & 0xefc60000u;
    y ^= y >> 18;
    return y;
  }
  uint32_t getrandbits(int k) { return genrand() >> (32 - k); }
  uint32_t randbelow(uint32_t n) {
    int k = 32 - __builtin_clz(n);
    uint32_t r = getrandbits(k);
    while (r >= n) r = getrandbits(k);
    return r;
  }
};

void build_gatelist(GateList& gl) {
  PyRandom rng;
  uint32_t key = 1024u;
  rng.init_by_array(&key, 1);
  static const int PC_S[7]  = {1, 1, 1, 0, 0, 1, 3};
  static const int PC_D[10] = {1, 1, 1, 0, 0, 1, 0, 3, 0, 0};
  int off = 0, idx = 0;
  for (int circ = 0; circ < 3; ++circ) {
    for (int blk = 0; blk < 3; ++blk) {
      for (int i = 0; i < 4; ++i) {
        int g = (int)rng.randbelow(7);            // choice(SINGLE)
        gl.ty[idx] = g; gl.q0[idx] = i; gl.q1[idx] = 0; gl.off[idx] = off;
        off += PC_S[g]; ++idx;
      }
      int pool[3] = {0, 1, 2};                    // sample(range(0,3), 2)
      int j0 = (int)rng.randbelow(3); int c = pool[j0]; pool[j0] = pool[2];
      int j1 = (int)rng.randbelow(2); int t = pool[j1];
      int g = (int)rng.randbelow(10);             // choice(DOUBLE)
      gl.ty[idx] = 10 + g; gl.q0[idx] = c; gl.q1[idx] = t; gl.off[idx] = off;
      off += PC_D[g]; ++idx;
    }
  }
}

__device__ inline float2 cmul(float2 a, float2 b) {
  return make_float2(a.x * b.x - a.y * b.y, a.x * b.y + a.y * b.x);
}
__device__ inline float2 cadd(float2 a, float2 b) {
  return make_float2(a.x + b.x, a.y + b.y);
}
__device__ inline float2 shflx(float2 v, int m) {
  return make_float2(__shfl_xor(v.x, m), __shfl_xor(v.y, m));
}

// ---------------------------------------------------------------------------
// Fused kernel. Block = 1024 threads (16 waves), 64 rows/wave, 512 blocks.
// Phase 1 (tid<768, waves 0..11): tid = circ*256 + col*16 + k; thread holds
// U[row=k][col] in a register, partners via shfl_xor (masks 1,2,4,8 stay in
// the 16-lane cluster). Folds (-i)^popc(col) phase, stores f16 A-fragments:
// block bb=2c(re)/2c+1(im); A[m][kk] -> lane L=(kk>>3)*16+m, slot j=kk&7.
// Phase 2 (all waves): rr[16] per row -> f16 -> LDS (stride 24 halves; rr
// reads are wave-local so only ONE barrier needed, for the U fragments).
// ---------------------------------------------------------------------------
__global__ __launch_bounds__(1024, 4) void qconv_fused(
    const float* __restrict__ x, const float* __restrict__ params,
    float* __restrict__ out, GateList gl) {
  __shared__ _Float16 ufrag[1536];       // 3 KB: 6 blocks x 32 lanes x 8
  __shared__ _Float16 lds[1024 * 24];    // 48 KB rr staging

  const int tid  = threadIdx.x;
  const int wid  = tid >> 6;
  const int lane = tid & 63;
  const int quad = lane >> 4;
  const int n16  = lane & 15;
  const int rowbase = blockIdx.x * 1024 + wid * 64;
  const int r = rowbase + lane;

  // ---- issue x loads early (prefetch across the build chain) ----
  const int b  = r >> 10;
  const int h2 = (r >> 5) & 31;
  const int j  = r & 31;
  const float* xb = x + b * 4096 + h2 * 128 + j * 2;
  float2 lo = *(const float2*)(xb);        // row 2h2:  [2j], [2j+1]
  float2 hi = *(const float2*)(xb + 64);   // row 2h2+1:[2j], [2j+1]

  // ---- phase 1: per-block unitary build (waves 0..11) ----
  if (tid < 768) {
    const int circ = tid >> 8;
    const int col  = (tid >> 4) & 15;
    const int k    = tid & 15;

    float2 s = make_float2(k == col ? 1.f : 0.f, 0.f);

    for (int g = 0; g < 15; ++g) {
      int gi = circ * 15 + g;
      int ty = gl.ty[gi];
      int o  = gl.off[gi];
      if (ty < 7) {
        float2 G00 = make_float2(1, 0), G01 = make_float2(0, 0),
               G10 = make_float2(0, 0), G11 = make_float2(1, 0);
        if (ty == 0) {                 // rx
          float c, sn; __sincosf(params[o] * 0.5f, &sn, &c);
          G00 = make_float2(c, 0); G01 = make_float2(0, -sn);
          G10 = make_float2(0, -sn); G11 = make_float2(c, 0);
        } else if (ty == 1) {          // ry
          float c, sn; __sincosf(params[o] * 0.5f, &sn, &c);
          G00 = make_float2(c, 0); G01 = make_float2(-sn, 0);
          G10 = make_float2(sn, 0); G11 = make_float2(c, 0);
        } else if (ty == 2) {          // rz
          float c, sn; __sincosf(params[o] * 0.5f, &sn, &c);
          G00 = make_float2(c, -sn); G11 = make_float2(c, sn);
        } else if (ty == 3) {          // s
          G11 = make_float2(0, 1);
        } else if (ty == 4) {          // t
          G11 = make_float2(0.7071067811865476f, 0.7071067811865476f);
        } else if (ty == 5) {          // p
          float cp, sp; __sincosf(params[o], &sp, &cp);
          G11 = make_float2(cp, sp);
        } else {                       // u3
          float th = params[o], phv = params[o + 1], lm = params[o + 2];
          float c, sn; __sincosf(th * 0.5f, &sn, &c);
          float cp, sp; __sincosf(phv, &sp, &cp);
          float cl, sl; __sincosf(lm, &sl, &cl);
          G00 = make_float2(c, 0);
          G01 = make_float2(-cl * sn, -sl * sn);
          G10 = make_float2(cp * sn, sp * sn);
          G11 = make_float2((cp * cl - sp * sl) * c, (cp * sl + sp * cl) * c);
        }
        int m = 1 << (3 - gl.q0[gi]);
        bool hib = (k & m) != 0;
        float2 p = shflx(s, m);
        float2 A = hib ? G11 : G00;
        float2 B = hib ? G10 : G01;
        s = cadd(cmul(A, s), cmul(B, p));
      } else {
        float2 G[4][4];
#pragma unroll
        for (int r2 = 0; r2 < 4; ++r2)
#pragma unroll
          for (int c2 = 0; c2 < 4; ++c2) G[r2][c2] = make_float2(0, 0);
        if (ty == 10) {                // rxx
          float c, sn; __sincosf(params[o] * 0.5f, &sn, &c);
          G[0][0] = G[1][1] = G[2][2] = G[3][3] = make_float2(c, 0);
          G[0][3] = G[1][2] = G[2][1] = G[3][0] = make_float2(0, -sn);
        } else if (ty == 11) {         // ryy
          float c, sn; __sincosf(params[o] * 0.5f, &sn, &c);
          G[0][0] = G[1][1] = G[2][2] = G[3][3] = make_float2(c, 0);
          G[0][3] = G[3][0] = make_float2(0, sn);
          G[1][2] = G[2][1] = make_float2(0, -sn);
        } else if (ty == 12) {         // rzz
          float c, sn; __sincosf(params[o] * 0.5f, &sn, &c);
          G[0][0] = G[3][3] = make_float2(c, -sn);
          G[1][1] = G[2][2] = make_float2(c, sn);
        } else if (ty == 13) {         // swap
          G[0][0] = make_float2(1, 0); G[1][2] = make_float2(1, 0);
          G[2][1] = make_float2(1, 0); G[3][3] = make_float2(1, 0);
        } else if (ty == 14) {         // cnot
          G[0][0] = G[1][1] = make_float2(1, 0);
          G[2][3] = G[3][2] = make_float2(1, 0);
        } else if (ty == 15) {         // cp
          G[0][0] = G[1][1] = G[2][2] = make_float2(1, 0);
          float cp, sp; __sincosf(params[o], &sp, &cp);
          G[3][3] = make_float2(cp, sp);
        } else if (ty == 16) {         // ch
          G[0][0] = G[1][1] = make_float2(1, 0);
          float rv = 0.7071067811865476f;
          G[2][2] = make_float2(rv, 0); G[2][3] = make_float2(rv, 0);
          G[3][2] = make_float2(rv, 0); G[3][3] = make_float2(-rv, 0);
        } else if (ty == 17) {         // cu
          G[0][0] = G[1][1] = make_float2(1, 0);
          float th = params[o], phv = params[o + 1], lm = params[o + 2];
          float c, sn; __sincosf(th * 0.5f, &sn, &c);
          float cp, sp; __sincosf(phv, &sp, &cp);
          float cl, sl; __sincosf(lm, &sl, &cl);
          G[2][2] = make_float2(c, 0);
          G[2][3] = make_float2(-cl * sn, -sl * sn);
          G[3][2] = make_float2(cp * sn, sp * sn);
          G[3][3] = make_float2((cp * cl - sp * sl) * c, (cp * sl + sp * cl) * c);
        } else if (ty == 18) {         // ct
          G[0][0] = G[1][1] = G[2][2] = make_float2(1, 0);
          G[3][3] = make_float2(0.7071067811865476f, 0.7071067811865476f);
        } else {                       // cz
          G[0][0] = G[1][1] = G[2][2] = make_float2(1, 0);
          G[3][3] = make_float2(-1, 0);
        }
        int m0 = 1 << (3 - gl.q0[gi]);
        int m1 = 1 << (3 - gl.q1[gi]);
        bool b0 = (k & m0) != 0;
        bool b1 = (k & m1) != 0;
        float2 p0 = s;
        float2 p1 = shflx(s, m1);
        float2 p2 = shflx(s, m0);
        float2 p3 = shflx(s, m0 ^ m1);
        float2 acc = make_float2(0, 0);
#pragma unroll
        for (int jj = 0; jj < 4; ++jj) {
          float2 r0 = b1 ? G[1][1 ^ jj] : G[0][0 ^ jj];
          float2 r1 = b1 ? G[3][3 ^ jj] : G[2][2 ^ jj];
          float2 coef = b0 ? r1 : r0;
          float2 pj = (jj == 0) ? p0 : (jj == 1) ? p1 : (jj == 2) ? p2 : p3;
          acc = cadd(acc, cmul(coef, pj));
        }
        s = acc;
      }
    }

    // fold initial-state phase (-i)^popcount(col)
    int pc = __popc(col) & 3;
    float2 ph = make_float2(1, 0);
    if (pc == 1) ph = make_float2(0, -1);
    else if (pc == 2) ph = make_float2(-1, 0);
    else if (pc == 3) ph = make_float2(0, 1);
    float2 v = cmul(s, ph);

    int L = ((col >> 3) << 4) | k;   // 0..31
    int jf = col & 7;
    ufrag[((2 * circ) * 32 + L) * 8 + jf]     = (_Float16)v.x;
    ufrag[((2 * circ + 1) * 32 + L) * 8 + jf] = (_Float16)v.y;
  }

  // ---- phase 2a: rr compute + wave-local staging (no barrier needed) ----
  float c0, s0, c1, s1, c2, s2, c3, s3;
  __sincosf(lo.x * 0.5f, &s0, &c0);
  __sincosf(hi.x * 0.5f, &s1, &c1);
  __sincosf(lo.y * 0.5f, &s2, &c2);
  __sincosf(hi.y * 0.5f, &s3, &c3);
  float t01[4] = {c0 * c1, c0 * s1, s0 * c1, s0 * s1};
  float t23[4] = {c2 * c3, c2 * s3, s2 * c3, s2 * s3};
  __align__(16) _Float16 rh[16];
#pragma unroll
  for (int a = 0; a < 4; ++a)
#pragma unroll
    for (int bq = 0; bq < 4; ++bq)
      rh[a * 4 + bq] = (_Float16)(t01[a] * t23[bq]);

  half8* dst = (half8*)&lds[tid * 24];
  dst[0] = *(const half8*)&rh[0];
  dst[1] = *(const half8*)&rh[8];

  __syncthreads();   // publish ufrag (rr staging is wave-local)

  // ---- A-operand fragments; lanes >= 32 supply the K=16..31 zeros ----
  half8 af[6];
  if (lane < 32) {
    const half8* Uv = (const half8*)ufrag;
#pragma unroll
    for (int bb = 0; bb < 6; ++bb) af[bb] = Uv[bb * 32 + lane];
  } else {
#pragma unroll
    for (int bb = 0; bb < 6; ++bb)
#pragma unroll
      for (int e = 0; e < 8; ++e) af[bb][e] = (_Float16)0.f;
  }

  // ---- phase 2b: MFMA + epilogue per 16-row set ----
#pragma unroll
  for (int t = 0; t < 4; ++t) {
    half8 bf;
    if (quad < 2) {
      bf = *(const half8*)&lds[(wid * 64 + t * 16 + n16) * 24 + quad * 8];
    } else {
#pragma unroll
      for (int e = 0; e < 8; ++e) bf[e] = (_Float16)0.f;
    }
    float4v acc[6];
#pragma unroll
    for (int bb = 0; bb < 6; ++bb) {
      float4v z = {0.f, 0.f, 0.f, 0.f};
      acc[bb] = __builtin_amdgcn_mfma_f32_16x16x32_f16(af[bb], bf, z, 0, 0, 0);
    }
    float4 E[3];
#pragma unroll
    for (int c = 0; c < 3; ++c) {
      float pv[4];
#pragma unroll
      for (int v = 0; v < 4; ++v) {
        float re = acc[2 * c][v], im = acc[2 * c + 1][v];
        pv[v] = fmaf(re, re, im * im);
      }
      // i = quad*4 + v; sign bits: q0<-i&8, q1<-i&4, q2<-i&2, q3<-i&1
      float sA = pv[0] + pv[1], dA = pv[0] - pv[1];
      float sB = pv[2] + pv[3], dB = pv[2] - pv[3];
      float A00 = sA + sB;   // no v-sign (q0,q1)
      float A01 = dA + dB;   // sign on i bit0 (q3)
      float A10 = sA - sB;   // sign on i bit1 (q2)
      float r3 = A01 + __shfl_xor(A01, 16); r3 += __shfl_xor(r3, 32);
      float r2 = A10 + __shfl_xor(A10, 16); r2 += __shfl_xor(r2, 32);
      float h16v = __shfl_xor(A00, 16);
      float Ssum = A00 + h16v;
      float Dv = (quad & 1) ? (h16v - A00) : (A00 - h16v);
      float r1 = Dv + __shfl_xor(Dv, 32);
      float S32 = __shfl_xor(Ssum, 32);
      float r0 = (quad & 2) ? (S32 - Ssum) : (Ssum - S32);
      E[c] = make_float4(r0, r1, r2, r3);
    }
    if (quad < 3) {
      float4 ev = (quad == 0) ? E[0] : (quad == 1 ? E[1] : E[2]);
      int rowg = rowbase + t * 16 + n16;
      *(float4*)(out + (size_t)rowg * 12 + quad * 4) = ev;
    }
  }
}

}  // namespace

extern "C" void kernel_launch(void* const* d_in, const int* in_sizes, int n_in,
                              void* d_out, int out_size, void* d_ws, size_t ws_size,
                              hipStream_t stream) {
  const float* x      = (const float*)d_in[0];
  const float* params = (const float*)d_in[1];
  float* out = (float*)d_out;
  (void)d_ws; (void)ws_size;

  GateList gl;
  build_gatelist(gl);                // deterministic every call (seed 1024)

  int nrows = in_sizes[0] / 4;       // 524288
  int grid  = nrows / 1024;          // 512 blocks x 16 waves x 64 rows
  hipLaunchKernelGGL(qconv_fused, dim3(grid), dim3(1024), 0, stream,
                     x, params, out, gl);
}

// Round 5
// 82.924 us; speedup vs baseline: 1.1196x; 1.1196x over previous
//
#include <hip/hip_runtime.h>
#include <stdint.h>

// ---------------------------------------------------------------------------
// RandomParameterizedQuantumConvolutionLayer — linear-form reformulation.
// Identity: out[row, c, q] = sum_i sign_q(i) |sum_k U'_c[i,k] r_k|^2 with
// r = tensor_q (cos h_q, sin h_q), h=a/2. Since cos^2 h=(1+cos a)/2 etc.,
// out is LINEAR in g = tensor_q (1, cos a_q, sin a_q)  (81 features):
//     out(12 x N) = T(12 x 81) . G(81 x N)
// build_T (768 thr, 1 block): U' via register+shfl -> A_cq[k,l] =
// sum_i sign_q(i) Re(U'[i,k] conj(U'[i,l])) -> per-qubit (2x2)->3 contraction
// -> T, split hi/lo f16, stored as mfma A-fragments in d_ws (zero-filled).
// qconv_main: per lane: 4 sincos + ~110 mul -> g[96] f16 -> LDS (row stride
// 104 halves, 2-way bank aliasing = free) -> per 16-row set 3 ds_read_b128 +
// 6 chained mfma_f32_16x16x32_f16 -> C-layout float4 store. No epilogue.
// ---------------------------------------------------------------------------

namespace {

typedef _Float16 half8 __attribute__((ext_vector_type(8)));
typedef float float4v __attribute__((ext_vector_type(4)));

struct GateList {
  int ty[45];   // 0..6 single (rx,ry,rz,s,t,p,u3); 10..19 double
  int q0[45];
  int q1[45];
  int off[45];  // param offset
};

// ---- CPython-compatible MT19937 (random.Random) ----
struct PyRandom {
  uint32_t mt[624];
  int mti;
  void init_genrand(uint32_t s) {
    mt[0] = s;
    for (int i = 1; i < 624; ++i)
      mt[i] = 1812433253u * (mt[i - 1] ^ (mt[i - 1] >> 30)) + (uint32_t)i;
    mti = 624;
  }
  void init_by_array(const uint32_t* key, int klen) {
    init_genrand(19650218u);
    int i = 1, j = 0;
    int k = 624 > klen ? 624 : klen;
    for (; k; --k) {
      mt[i] = (mt[i] ^ ((mt[i - 1] ^ (mt[i - 1] >> 30)) * 1664525u)) + key[j] + (uint32_t)j;
      ++i; ++j;
      if (i >= 624) { mt[0] = mt[623]; i = 1; }
      if (j >= klen) j = 0;
    }
    for (k = 623; k; --k) {
      mt[i] = (mt[i] ^ ((mt[i - 1] ^ (mt[i - 1] >> 30)) * 1566083941u)) - (uint32_t)i;
      ++i;
      if (i >= 624) { mt[0] = mt[623]; i = 1; }
    }
    mt[0] = 0x80000000u;
    mti = 624;
  }
  uint32_t genrand() {
    if (mti >= 624) {
      const uint32_t mag[2] = {0u, 0x9908b0dfu};
      int kk; uint32_t y;
      for (kk = 0; kk < 227; ++kk) {
        y = (mt[kk] & 0x80000000u) | (mt[kk + 1] & 0x7fffffffu);
        mt[kk] = mt[kk + 397] ^ (y >> 1) ^ mag[y & 1];
      }
      for (; kk < 623; ++kk) {
        y = (mt[kk] & 0x80000000u) | (mt[kk + 1] & 0x7fffffffu);
        mt[kk] = mt[kk - 227] ^ (y >> 1) ^ mag[y & 1];
      }
      y = (mt[623] & 0x80000000u) | (mt[0] & 0x7fffffffu);
      mt[623] = mt[396] ^ (y >> 1) ^ mag[y & 1];
      mti = 0;
    }
    uint32_t y = mt[mti++];
    y ^= y >> 11;
    y ^= (y << 7) & 0x9d2c5680u;
    y ^= (y << 15) & 0xefc60000u;
    y ^= y >> 18;
    return y;
  }
  uint32_t getrandbits(int k) { return genrand() >> (32 - k); }
  uint32_t randbelow(uint32_t n) {
    int k = 32 - __builtin_clz(n);
    uint32_t r = getrandbits(k);
    while (r >= n) r = getrandbits(k);
    return r;
  }
};

void build_gatelist(GateList& gl) {
  PyRandom rng;
  uint32_t key = 1024u;
  rng.init_by_array(&key, 1);
  static const int PC_S[7]  = {1, 1, 1, 0, 0, 1, 3};
  static const int PC_D[10] = {1, 1, 1, 0, 0, 1, 0, 3, 0, 0};
  int off = 0, idx = 0;
  for (int circ = 0; circ < 3; ++circ) {
    for (int blk = 0; blk < 3; ++blk) {
      for (int i = 0; i < 4; ++i) {
        int g = (int)rng.randbelow(7);            // choice(SINGLE)
        gl.ty[idx] = g; gl.q0[idx] = i; gl.q1[idx] = 0; gl.off[idx] = off;
        off += PC_S[g]; ++idx;
      }
      int pool[3] = {0, 1, 2};                    // sample(range(0,3), 2)
      int j0 = (int)rng.randbelow(3); int c = pool[j0]; pool[j0] = pool[2];
      int j1 = (int)rng.randbelow(2); int t = pool[j1];
      int g = (int)rng.randbelow(10);             // choice(DOUBLE)
      gl.ty[idx] = 10 + g; gl.q0[idx] = c; gl.q1[idx] = t; gl.off[idx] = off;
      off += PC_D[g]; ++idx;
    }
  }
}

__device__ inline float2 cmul(float2 a, float2 b) {
  return make_float2(a.x * b.x - a.y * b.y, a.x * b.y + a.y * b.x);
}
__device__ inline float2 cadd(float2 a, float2 b) {
  return make_float2(a.x + b.x, a.y + b.y);
}
__device__ inline float2 shflx(float2 v, int m) {
  return make_float2(__shfl_xor(v.x, m), __shfl_xor(v.y, m));
}

// ---------------------------------------------------------------------------
// build_T: one 768-thread block.
// Phase A: tid = circ*256 + col*16 + k -> U'[row=k][col] in register (proven
//   register+shfl circuit evaluation, phase (-i)^popc(col) folded) -> LDS.
// Phase B: tid = circ*256 + k*16 + l -> A_cq[k][l] for q=0..3 -> LDS.
// Phase C: 972 outputs T[cq][j] (j in base-3 over qubits), each a 16-term
//   signed sum of A entries; split hi/lo f16; store as mfma A-fragments.
// d_ws layout (halves): chunk(mf=0..2) x {hi,lo}: [(mf*2+hl)*64 + L]*8 + jj,
// L = (kk>>3)*16 + m, jj = kk&7, kk = j&31, m = c*4+q. 3072 halves total.
// ---------------------------------------------------------------------------
__global__ __launch_bounds__(768) void build_T(
    const float* __restrict__ params, _Float16* __restrict__ Tws, GateList gl) {
  __shared__ float2 ldsU[768];    // U'[c][row][col] at (c*16+row)*16+col
  __shared__ float  ldsA[3072];   // A[cq][k][l] at ((cq)*16+k)*16+l

  const int tid = threadIdx.x;

  // zero the whole fragment region (d_ws is poisoned 0xAA every launch)
  ((uint64_t*)Tws)[tid] = 0ull;   // 768 * 8B = 6144B = 3072 halves

  // ---- phase A: circuit evaluation ----
  {
    const int circ = tid >> 8;
    const int col  = (tid >> 4) & 15;
    const int k    = tid & 15;

    float2 s = make_float2(k == col ? 1.f : 0.f, 0.f);

    for (int g = 0; g < 15; ++g) {
      int gi = circ * 15 + g;
      int ty = gl.ty[gi];
      int o  = gl.off[gi];
      if (ty < 7) {
        float2 G00 = make_float2(1, 0), G01 = make_float2(0, 0),
               G10 = make_float2(0, 0), G11 = make_float2(1, 0);
        if (ty == 0) {                 // rx
          float c, sn; __sincosf(params[o] * 0.5f, &sn, &c);
          G00 = make_float2(c, 0); G01 = make_float2(0, -sn);
          G10 = make_float2(0, -sn); G11 = make_float2(c, 0);
        } else if (ty == 1) {          // ry
          float c, sn; __sincosf(params[o] * 0.5f, &sn, &c);
          G00 = make_float2(c, 0); G01 = make_float2(-sn, 0);
          G10 = make_float2(sn, 0); G11 = make_float2(c, 0);
        } else if (ty == 2) {          // rz
          float c, sn; __sincosf(params[o] * 0.5f, &sn, &c);
          G00 = make_float2(c, -sn); G11 = make_float2(c, sn);
        } else if (ty == 3) {          // s
          G11 = make_float2(0, 1);
        } else if (ty == 4) {          // t
          G11 = make_float2(0.7071067811865476f, 0.7071067811865476f);
        } else if (ty == 5) {          // p
          float cp, sp; __sincosf(params[o], &sp, &cp);
          G11 = make_float2(cp, sp);
        } else {                       // u3
          float th = params[o], phv = params[o + 1], lm = params[o + 2];
          float c, sn; __sincosf(th * 0.5f, &sn, &c);
          float cp, sp; __sincosf(phv, &sp, &cp);
          float cl, sl; __sincosf(lm, &sl, &cl);
          G00 = make_float2(c, 0);
          G01 = make_float2(-cl * sn, -sl * sn);
          G10 = make_float2(cp * sn, sp * sn);
          G11 = make_float2((cp * cl - sp * sl) * c, (cp * sl + sp * cl) * c);
        }
        int m = 1 << (3 - gl.q0[gi]);
        bool hib = (k & m) != 0;
        float2 p = shflx(s, m);
        float2 A = hib ? G11 : G00;
        float2 B = hib ? G10 : G01;
        s = cadd(cmul(A, s), cmul(B, p));
      } else {
        float2 G[4][4];
#pragma unroll
        for (int r2 = 0; r2 < 4; ++r2)
#pragma unroll
          for (int c2 = 0; c2 < 4; ++c2) G[r2][c2] = make_float2(0, 0);
        if (ty == 10) {                // rxx
          float c, sn; __sincosf(params[o] * 0.5f, &sn, &c);
          G[0][0] = G[1][1] = G[2][2] = G[3][3] = make_float2(c, 0);
          G[0][3] = G[1][2] = G[2][1] = G[3][0] = make_float2(0, -sn);
        } else if (ty == 11) {         // ryy
          float c, sn; __sincosf(params[o] * 0.5f, &sn, &c);
          G[0][0] = G[1][1] = G[2][2] = G[3][3] = make_float2(c, 0);
          G[0][3] = G[3][0] = make_float2(0, sn);
          G[1][2] = G[2][1] = make_float2(0, -sn);
        } else if (ty == 12) {         // rzz
          float c, sn; __sincosf(params[o] * 0.5f, &sn, &c);
          G[0][0] = G[3][3] = make_float2(c, -sn);
          G[1][1] = G[2][2] = make_float2(c, sn);
        } else if (ty == 13) {         // swap
          G[0][0] = make_float2(1, 0); G[1][2] = make_float2(1, 0);
          G[2][1] = make_float2(1, 0); G[3][3] = make_float2(1, 0);
        } else if (ty == 14) {         // cnot
          G[0][0] = G[1][1] = make_float2(1, 0);
          G[2][3] = G[3][2] = make_float2(1, 0);
        } else if (ty == 15) {         // cp
          G[0][0] = G[1][1] = G[2][2] = make_float2(1, 0);
          float cp, sp; __sincosf(params[o], &sp, &cp);
          G[3][3] = make_float2(cp, sp);
        } else if (ty == 16) {         // ch
          G[0][0] = G[1][1] = make_float2(1, 0);
          float rv = 0.7071067811865476f;
          G[2][2] = make_float2(rv, 0); G[2][3] = make_float2(rv, 0);
          G[3][2] = make_float2(rv, 0); G[3][3] = make_float2(-rv, 0);
        } else if (ty == 17) {         // cu
          G[0][0] = G[1][1] = make_float2(1, 0);
          float th = params[o], phv = params[o + 1], lm = params[o + 2];
          float c, sn; __sincosf(th * 0.5f, &sn, &c);
          float cp, sp; __sincosf(phv, &sp, &cp);
          float cl, sl; __sincosf(lm, &sl, &cl);
          G[2][2] = make_float2(c, 0);
          G[2][3] = make_float2(-cl * sn, -sl * sn);
          G[3][2] = make_float2(cp * sn, sp * sn);
          G[3][3] = make_float2((cp * cl - sp * sl) * c, (cp * sl + sp * cl) * c);
        } else if (ty == 18) {         // ct
          G[0][0] = G[1][1] = G[2][2] = make_float2(1, 0);
          G[3][3] = make_float2(0.7071067811865476f, 0.7071067811865476f);
        } else {                       // cz
          G[0][0] = G[1][1] = G[2][2] = make_float2(1, 0);
          G[3][3] = make_float2(-1, 0);
        }
        int m0 = 1 << (3 - gl.q0[gi]);
        int m1 = 1 << (3 - gl.q1[gi]);
        bool b0 = (k & m0) != 0;
        bool b1 = (k & m1) != 0;
        float2 p0 = s;
        float2 p1 = shflx(s, m1);
        float2 p2 = shflx(s, m0);
        float2 p3 = shflx(s, m0 ^ m1);
        float2 acc = make_float2(0, 0);
#pragma unroll
        for (int jj = 0; jj < 4; ++jj) {
          float2 r0 = b1 ? G[1][1 ^ jj] : G[0][0 ^ jj];
          float2 r1 = b1 ? G[3][3 ^ jj] : G[2][2 ^ jj];
          float2 coef = b0 ? r1 : r0;
          float2 pj = (jj == 0) ? p0 : (jj == 1) ? p1 : (jj == 2) ? p2 : p3;
          acc = cadd(acc, cmul(coef, pj));
        }
        s = acc;
      }
    }

    int pc = __popc(col) & 3;
    float2 ph = make_float2(1, 0);
    if (pc == 1) ph = make_float2(0, -1);
    else if (pc == 2) ph = make_float2(-1, 0);
    else if (pc == 3) ph = make_float2(0, 1);
    float2 v = cmul(s, ph);

    ldsU[(circ * 16 + k) * 16 + col] = v;   // U'[row=k][col]
  }
  __syncthreads();

  // ---- phase B: A_cq[k][l] = sum_i sign_q(i) Re(U'[i,k] conj(U'[i,l])) ----
  {
    const int circ = tid >> 8;
    const int k    = (tid >> 4) & 15;
    const int l    = tid & 15;
    float a0 = 0.f, a1 = 0.f, a2 = 0.f, a3 = 0.f;
    for (int i = 0; i < 16; ++i) {
      float2 uk = ldsU[(circ * 16 + i) * 16 + k];
      float2 ul = ldsU[(circ * 16 + i) * 16 + l];
      float t = uk.x * ul.x + uk.y * ul.y;
      a0 += (i & 8) ? -t : t;
      a1 += (i & 4) ? -t : t;
      a2 += (i & 2) ? -t : t;
      a3 += (i & 1) ? -t : t;
    }
    ldsA[((circ * 4 + 0) * 16 + k) * 16 + l] = a0;
    ldsA[((circ * 4 + 1) * 16 + k) * 16 + l] = a1;
    ldsA[((circ * 4 + 2) * 16 + k) * 16 + l] = a2;
    ldsA[((circ * 4 + 3) * 16 + k) * 16 + l] = a3;
  }
  __syncthreads();

  // ---- phase C: contract to T[cq][j], j base-3 over qubits ----
  // per qubit q with feature jq: (kq,lq,coef*2): jq=0 -> (t,t,+1);
  // jq=1 -> (t,t, t? -1:+1); jq=2 -> (t,1-t,+1).  T = (1/16) sum over t in 2^4.
  for (int idx = tid; idx < 972; idx += 768) {
    int cq = idx / 81;
    int j  = idx - cq * 81;
    int j0 = j / 27, j1 = (j / 9) % 3, j2 = (j % 9) / 3, j3 = j % 3;
    int jarr[4] = {j0, j1, j2, j3};
    float acc = 0.f;
    for (int sel = 0; sel < 16; ++sel) {
      int kk = 0, ll = 0;
      float sg = 1.f;
#pragma unroll
      for (int q = 0; q < 4; ++q) {
        int t = (sel >> (3 - q)) & 1;
        kk |= t << (3 - q);
        int lb = (jarr[q] == 2) ? (1 - t) : t;
        ll |= lb << (3 - q);
        if (jarr[q] == 1 && t) sg = -sg;
      }
      acc += sg * ldsA[(cq * 16 + kk) * 16 + ll];
    }
    float T = acc * 0.0625f;
    _Float16 th = (_Float16)T;
    _Float16 tl = (_Float16)(T - (float)th);
    int mf = j >> 5, kkc = j & 31;
    int L = ((kkc >> 3) << 4) | cq;
    int jj = kkc & 7;
    Tws[((mf * 2 + 0) * 64 + L) * 8 + jj] = th;
    Tws[((mf * 2 + 1) * 64 + L) * 8 + jj] = tl;
  }
}

// ---------------------------------------------------------------------------
// qconv_main: block = 256 threads (4 waves, 256 rows), grid 2048.
// Per lane: load 2x2 patch, 4 full-angle sincos, g[96] = tensor features ->
// f16 -> LDS (row stride 104 halves = 208B: bank starts n16*52%32 spread over
// 8 windows -> 2-way = free). Per 16-row set: 3 ds_read_b128 B-frags,
// 6 mfma_f32_16x16x32_f16 (hi/lo x 3 K-chunks, 4 independent acc chains),
// direct C-layout store: lane(quad,n16) holds channels quad*4..+3 of row n16.
// ---------------------------------------------------------------------------
__global__ __launch_bounds__(256, 3) void qconv_main(
    const float* __restrict__ x, const _Float16* __restrict__ T,
    float* __restrict__ out) {
  __shared__ _Float16 lds[256 * 104];
  const int tid  = threadIdx.x;
  const int wid  = tid >> 6;
  const int lane = tid & 63;
  const int quad = lane >> 4;
  const int n16  = lane & 15;
  const int r = blockIdx.x * 256 + tid;

  // A-fragments (T hi/lo per K-chunk)
  const half8* Tv = (const half8*)T;
  half8 afh[3], afl[3];
#pragma unroll
  for (int mf = 0; mf < 3; ++mf) {
    afh[mf] = Tv[(mf * 2 + 0) * 64 + lane];
    afl[mf] = Tv[(mf * 2 + 1) * 64 + lane];
  }

  // 2x2 patch -> 4 angles (qubit0=lo.x, 1=hi.x, 2=lo.y, 3=hi.y; as rounds 1-4)
  const int b  = r >> 10;
  const int h2 = (r >> 5) & 31;
  const int j  = r & 31;
  const float* xb = x + b * 4096 + h2 * 128 + j * 2;
  float2 lo = *(const float2*)(xb);
  float2 hi = *(const float2*)(xb + 64);
  float c0, s0, c1, s1, c2, s2, c3, s3;
  __sincosf(lo.x, &s0, &c0);
  __sincosf(hi.x, &s1, &c1);
  __sincosf(lo.y, &s2, &c2);
  __sincosf(hi.y, &s3, &c3);
  float f0[3] = {1.f, c0, s0}, f1[3] = {1.f, c1, s1};
  float f2[3] = {1.f, c2, s2}, f3[3] = {1.f, c3, s3};
  float g01e[11], g23[9];
#pragma unroll
  for (int a = 0; a < 9; ++a) g01e[a] = f0[a / 3] * f1[a % 3];
  g01e[9] = 0.f; g01e[10] = 0.f;           // pad j=81..95 -> zeros
#pragma unroll
  for (int bq = 0; bq < 9; ++bq) g23[bq] = f2[bq / 3] * f3[bq % 3];

#pragma unroll
  for (int w = 0; w < 12; ++w) {
    __align__(16) _Float16 h8[8];
#pragma unroll
    for (int e = 0; e < 8; ++e) {
      const int jg = w * 8 + e;            // compile-time
      h8[e] = (_Float16)(g01e[jg / 9] * g23[jg % 9]);
    }
    *(half8*)&lds[tid * 104 + w * 8] = *(const half8*)h8;
  }
  __syncthreads();

  // load all B-fragments, then 4 independent MFMA chains
  half8 bf[4][3];
#pragma unroll
  for (int t = 0; t < 4; ++t) {
    const int row = wid * 64 + t * 16 + n16;
#pragma unroll
    for (int mf = 0; mf < 3; ++mf)
      bf[t][mf] = *(const half8*)&lds[row * 104 + mf * 32 + quad * 8];
  }
  float4v acc[4];
#pragma unroll
  for (int t = 0; t < 4; ++t) acc[t] = (float4v){0.f, 0.f, 0.f, 0.f};
#pragma unroll
  for (int mf = 0; mf < 3; ++mf) {
#pragma unroll
    for (int t = 0; t < 4; ++t)
      acc[t] = __builtin_amdgcn_mfma_f32_16x16x32_f16(afl[mf], bf[t][mf], acc[t], 0, 0, 0);
#pragma unroll
    for (int t = 0; t < 4; ++t)
      acc[t] = __builtin_amdgcn_mfma_f32_16x16x32_f16(afh[mf], bf[t][mf], acc[t], 0, 0, 0);
  }

  // C layout: col = lane&15 = data row, row = quad*4+v = channel (12 used)
  if (quad < 3) {
#pragma unroll
    for (int t = 0; t < 4; ++t) {
      int rowg = blockIdx.x * 256 + wid * 64 + t * 16 + n16;
      *(float4*)(out + (size_t)rowg * 12 + quad * 4) =
          make_float4(acc[t][0], acc[t][1], acc[t][2], acc[t][3]);
    }
  }
}

}  // namespace

extern "C" void kernel_launch(void* const* d_in, const int* in_sizes, int n_in,
                              void* d_out, int out_size, void* d_ws, size_t ws_size,
                              hipStream_t stream) {
  const float* x      = (const float*)d_in[0];
  const float* params = (const float*)d_in[1];
  float* out = (float*)d_out;
  _Float16* Tws = (_Float16*)d_ws;   // 3072 halves (6 KB) used

  GateList gl;
  build_gatelist(gl);                // deterministic every call (seed 1024)

  hipLaunchKernelGGL(build_T, dim3(1), dim3(768), 0, stream, params, Tws, gl);

  int nrows = in_sizes[0] / 4;       // 524288
  int grid  = nrows / 256;           // 2048 blocks
  hipLaunchKernelGGL(qconv_main, dim3(grid), dim3(256), 0, stream,
                     x, Tws, out);
}

// Round 7
// 81.406 us; speedup vs baseline: 1.1404x; 1.0187x over previous
//
#include <hip/hip_runtime.h>
#include <stdint.h>

// ---------------------------------------------------------------------------
// RandomParameterizedQuantumConvolutionLayer — linear form out = T(12x81)·G.
// g factorizes: g[K] = f0[mf] * g123[r], K = mf*32+r (r<27 used), with
// f0 = {1, cos a0, sin a0}, g123 = f1 (x) f2 (x) f3. Rows stage only
// g123[32h] + f0[4h] (72 B) in LDS; consumer rebuilds B-fragments with 4
// packed f16 muls per (t,mf). build_T: register+shfl circuit eval -> A_cq ->
// per-qubit contraction -> T hi/lo f16 A-fragments in d_ws.
// ---------------------------------------------------------------------------

namespace {

typedef _Float16 half8 __attribute__((ext_vector_type(8)));
typedef _Float16 half4 __attribute__((ext_vector_type(4)));
typedef float float4v __attribute__((ext_vector_type(4)));

struct GateList {
  int ty[45];   // 0..6 single (rx,ry,rz,s,t,p,u3); 10..19 double
  int q0[45];
  int q1[45];
  int off[45];  // param offset
};

// ---- CPython-compatible MT19937 (random.Random) ----
struct PyRandom {
  uint32_t mt[624];
  int mti;
  void init_genrand(uint32_t s) {
    mt[0] = s;
    for (int i = 1; i < 624; ++i)
      mt[i] = 1812433253u * (mt[i - 1] ^ (mt[i - 1] >> 30)) + (uint32_t)i;
    mti = 624;
  }
  void init_by_array(const uint32_t* key, int klen) {
    init_genrand(19650218u);
    int i = 1, j = 0;
    int k = 624 > klen ? 624 : klen;
    for (; k; --k) {
      mt[i] = (mt[i] ^ ((mt[i - 1] ^ (mt[i - 1] >> 30)) * 1664525u)) + key[j] + (uint32_t)j;
      ++i; ++j;
      if (i >= 624) { mt[0] = mt[623]; i = 1; }
      if (j >= klen) j = 0;
    }
    for (k = 623; k; --k) {
      mt[i] = (mt[i] ^ ((mt[i - 1] ^ (mt[i - 1] >> 30)) * 1566083941u)) - (uint32_t)i;
      ++i;
      if (i >= 624) { mt[0] = mt[623]; i = 1; }
    }
    mt[0] = 0x80000000u;
    mti = 624;
  }
  uint32_t genrand() {
    if (mti >= 624) {
      const uint32_t mag[2] = {0u, 0x9908b0dfu};
      int kk; uint32_t y;
      for (kk = 0; kk < 227; ++kk) {
        y = (mt[kk] & 0x80000000u) | (mt[kk + 1] & 0x7fffffffu);
        mt[kk] = mt[kk + 397] ^ (y >> 1) ^ mag[y & 1];
      }
      for (; kk < 623; ++kk) {
        y = (mt[kk] & 0x80000000u) | (mt[kk + 1] & 0x7fffffffu);
        mt[kk] = mt[kk - 227] ^ (y >> 1) ^ mag[y & 1];
      }
      y = (mt[623] & 0x80000000u) | (mt[0] & 0x7fffffffu);
      mt[623] = mt[396] ^ (y >> 1) ^ mag[y & 1];
      mti = 0;
    }
    uint32_t y = mt[mti++];
    y ^= y >> 11;
    y ^= (y << 7) & 0x9d2c5680u;
    y ^= (y << 15) & 0xefc60000u;
    y ^= y >> 18;
    return y;
  }
  uint32_t getrandbits(int k) { return genrand() >> (32 - k); }
  uint32_t randbelow(uint32_t n) {
    int k = 32 - __builtin_clz(n);
    uint32_t r = getrandbits(k);
    while (r >= n) r = getrandbits(k);
    return r;
  }
};

void build_gatelist(GateList& gl) {
  PyRandom rng;
  uint32_t key = 1024u;
  rng.init_by_array(&key, 1);
  static const int PC_S[7]  = {1, 1, 1, 0, 0, 1, 3};
  static const int PC_D[10] = {1, 1, 1, 0, 0, 1, 0, 3, 0, 0};
  int off = 0, idx = 0;
  for (int circ = 0; circ < 3; ++circ) {
    for (int blk = 0; blk < 3; ++blk) {
      for (int i = 0; i < 4; ++i) {
        int g = (int)rng.randbelow(7);            // choice(SINGLE)
        gl.ty[idx] = g; gl.q0[idx] = i; gl.q1[idx] = 0; gl.off[idx] = off;
        off += PC_S[g]; ++idx;
      }
      int pool[3] = {0, 1, 2};                    // sample(range(0,3), 2)
      int j0 = (int)rng.randbelow(3); int c = pool[j0]; pool[j0] = pool[2];
      int j1 = (int)rng.randbelow(2); int t = pool[j1];
      int g = (int)rng.randbelow(10);             // choice(DOUBLE)
      gl.ty[idx] = 10 + g; gl.q0[idx] = c; gl.q1[idx] = t; gl.off[idx] = off;
      off += PC_D[g]; ++idx;
    }
  }
}

__device__ inline float2 cmul(float2 a, float2 b) {
  return make_float2(a.x * b.x - a.y * b.y, a.x * b.y + a.y * b.x);
}
__device__ inline float2 cadd(float2 a, float2 b) {
  return make_float2(a.x + b.x, a.y + b.y);
}
__device__ inline float2 shflx(float2 v, int m) {
  return make_float2(__shfl_xor(v.x, m), __shfl_xor(v.y, m));
}

// ---------------------------------------------------------------------------
// build_T: one 768-thread block.
// Phase A: tid = circ*256 + col*16 + k -> U'[row=k][col] in register.
// Phase B: A_cq[k][l] = sum_i sign_q(i) Re(U'[i,k] conj(U'[i,l])).
// Phase C: T[cq][K], K = mf*32 + r, feature = f_{q0}[mf]*f_{q1}[r/9]*
//   f_{q2}[(r/3)%3]*f_{q3}[r%3] (f = {1,cos,sin}); r>=27 stays zero.
//   Split hi/lo f16; store as mfma A-fragments: lane L=(r>>3)*16+cq, slot r&7.
// ---------------------------------------------------------------------------
__global__ __launch_bounds__(768) void build_T(
    const float* __restrict__ params, _Float16* __restrict__ Tws, GateList gl) {
  __shared__ float2 ldsU[768];    // U'[c][row][col] at (c*16+row)*16+col
  __shared__ float  ldsA[3072];   // A[cq][k][l] at ((cq)*16+k)*16+l

  const int tid = threadIdx.x;

  // zero the fragment region (d_ws is poisoned 0xAA every launch)
  ((uint64_t*)Tws)[tid] = 0ull;   // 768 * 8B = 3072 halves

  // ---- phase A: circuit evaluation ----
  {
    const int circ = tid >> 8;
    const int col  = (tid >> 4) & 15;
    const int k    = tid & 15;

    float2 s = make_float2(k == col ? 1.f : 0.f, 0.f);

    for (int g = 0; g < 15; ++g) {
      int gi = circ * 15 + g;
      int ty = gl.ty[gi];
      int o  = gl.off[gi];
      if (ty < 7) {
        float2 G00 = make_float2(1, 0), G01 = make_float2(0, 0),
               G10 = make_float2(0, 0), G11 = make_float2(1, 0);
        if (ty == 0) {                 // rx
          float c, sn; __sincosf(params[o] * 0.5f, &sn, &c);
          G00 = make_float2(c, 0); G01 = make_float2(0, -sn);
          G10 = make_float2(0, -sn); G11 = make_float2(c, 0);
        } else if (ty == 1) {          // ry
          float c, sn; __sincosf(params[o] * 0.5f, &sn, &c);
          G00 = make_float2(c, 0); G01 = make_float2(-sn, 0);
          G10 = make_float2(sn, 0); G11 = make_float2(c, 0);
        } else if (ty == 2) {          // rz
          float c, sn; __sincosf(params[o] * 0.5f, &sn, &c);
          G00 = make_float2(c, -sn); G11 = make_float2(c, sn);
        } else if (ty == 3) {          // s
          G11 = make_float2(0, 1);
        } else if (ty == 4) {          // t
          G11 = make_float2(0.7071067811865476f, 0.7071067811865476f);
        } else if (ty == 5) {          // p
          float cp, sp; __sincosf(params[o], &sp, &cp);
          G11 = make_float2(cp, sp);
        } else {                       // u3
          float th = params[o], phv = params[o + 1], lm = params[o + 2];
          float c, sn; __sincosf(th * 0.5f, &sn, &c);
          float cp, sp; __sincosf(phv, &sp, &cp);
          float cl, sl; __sincosf(lm, &sl, &cl);
          G00 = make_float2(c, 0);
          G01 = make_float2(-cl * sn, -sl * sn);
          G10 = make_float2(cp * sn, sp * sn);
          G11 = make_float2((cp * cl - sp * sl) * c, (cp * sl + sp * cl) * c);
        }
        int m = 1 << (3 - gl.q0[gi]);
        bool hib = (k & m) != 0;
        float2 p = shflx(s, m);
        float2 A = hib ? G11 : G00;
        float2 B = hib ? G10 : G01;
        s = cadd(cmul(A, s), cmul(B, p));
      } else {
        float2 G[4][4];
#pragma unroll
        for (int r2 = 0; r2 < 4; ++r2)
#pragma unroll
          for (int c2 = 0; c2 < 4; ++c2) G[r2][c2] = make_float2(0, 0);
        if (ty == 10) {                // rxx
          float c, sn; __sincosf(params[o] * 0.5f, &sn, &c);
          G[0][0] = G[1][1] = G[2][2] = G[3][3] = make_float2(c, 0);
          G[0][3] = G[1][2] = G[2][1] = G[3][0] = make_float2(0, -sn);
        } else if (ty == 11) {         // ryy
          float c, sn; __sincosf(params[o] * 0.5f, &sn, &c);
          G[0][0] = G[1][1] = G[2][2] = G[3][3] = make_float2(c, 0);
          G[0][3] = G[3][0] = make_float2(0, sn);
          G[1][2] = G[2][1] = make_float2(0, -sn);
        } else if (ty == 12) {         // rzz
          float c, sn; __sincosf(params[o] * 0.5f, &sn, &c);
          G[0][0] = G[3][3] = make_float2(c, -sn);
          G[1][1] = G[2][2] = make_float2(c, sn);
        } else if (ty == 13) {         // swap
          G[0][0] = make_float2(1, 0); G[1][2] = make_float2(1, 0);
          G[2][1] = make_float2(1, 0); G[3][3] = make_float2(1, 0);
        } else if (ty == 14) {         // cnot
          G[0][0] = G[1][1] = make_float2(1, 0);
          G[2][3] = G[3][2] = make_float2(1, 0);
        } else if (ty == 15) {         // cp
          G[0][0] = G[1][1] = G[2][2] = make_float2(1, 0);
          float cp, sp; __sincosf(params[o], &sp, &cp);
          G[3][3] = make_float2(cp, sp);
        } else if (ty == 16) {         // ch
          G[0][0] = G[1][1] = make_float2(1, 0);
          float rv = 0.7071067811865476f;
          G[2][2] = make_float2(rv, 0); G[2][3] = make_float2(rv, 0);
          G[3][2] = make_float2(rv, 0); G[3][3] = make_float2(-rv, 0);
        } else if (ty == 17) {         // cu
          G[0][0] = G[1][1] = make_float2(1, 0);
          float th = params[o], phv = params[o + 1], lm = params[o + 2];
          float c, sn; __sincosf(th * 0.5f, &sn, &c);
          float cp, sp; __sincosf(phv, &sp, &cp);
          float cl, sl; __sincosf(lm, &sl, &cl);
          G[2][2] = make_float2(c, 0);
          G[2][3] = make_float2(-cl * sn, -sl * sn);
          G[3][2] = make_float2(cp * sn, sp * sn);
          G[3][3] = make_float2((cp * cl - sp * sl) * c, (cp * sl + sp * cl) * c);
        } else if (ty == 18) {         // ct
          G[0][0] = G[1][1] = G[2][2] = make_float2(1, 0);
          G[3][3] = make_float2(0.7071067811865476f, 0.7071067811865476f);
        } else {                       // cz
          G[0][0] = G[1][1] = G[2][2] = make_float2(1, 0);
          G[3][3] = make_float2(-1, 0);
        }
        int m0 = 1 << (3 - gl.q0[gi]);
        int m1 = 1 << (3 - gl.q1[gi]);
        bool b0 = (k & m0) != 0;
        bool b1 = (k & m1) != 0;
        float2 p0 = s;
        float2 p1 = shflx(s, m1);
        float2 p2 = shflx(s, m0);
        float2 p3 = shflx(s, m0 ^ m1);
        float2 acc = make_float2(0, 0);
#pragma unroll
        for (int jj = 0; jj < 4; ++jj) {
          float2 r0 = b1 ? G[1][1 ^ jj] : G[0][0 ^ jj];
          float2 r1 = b1 ? G[3][3 ^ jj] : G[2][2 ^ jj];
          float2 coef = b0 ? r1 : r0;
          float2 pj = (jj == 0) ? p0 : (jj == 1) ? p1 : (jj == 2) ? p2 : p3;
          acc = cadd(acc, cmul(coef, pj));
        }
        s = acc;
      }
    }

    int pc = __popc(col) & 3;
    float2 ph = make_float2(1, 0);
    if (pc == 1) ph = make_float2(0, -1);
    else if (pc == 2) ph = make_float2(-1, 0);
    else if (pc == 3) ph = make_float2(0, 1);
    float2 v = cmul(s, ph);

    ldsU[(circ * 16 + k) * 16 + col] = v;   // U'[row=k][col]
  }
  __syncthreads();

  // ---- phase B ----
  {
    const int circ = tid >> 8;
    const int k    = (tid >> 4) & 15;
    const int l    = tid & 15;
    float a0 = 0.f, a1 = 0.f, a2 = 0.f, a3 = 0.f;
#pragma unroll
    for (int i = 0; i < 16; ++i) {
      float2 uk = ldsU[(circ * 16 + i) * 16 + k];
      float2 ul = ldsU[(circ * 16 + i) * 16 + l];
      float t = uk.x * ul.x + uk.y * ul.y;
      a0 += (i & 8) ? -t : t;
      a1 += (i & 4) ? -t : t;
      a2 += (i & 2) ? -t : t;
      a3 += (i & 1) ? -t : t;
    }
    ldsA[((circ * 4 + 0) * 16 + k) * 16 + l] = a0;
    ldsA[((circ * 4 + 1) * 16 + k) * 16 + l] = a1;
    ldsA[((circ * 4 + 2) * 16 + k) * 16 + l] = a2;
    ldsA[((circ * 4 + 3) * 16 + k) * 16 + l] = a3;
  }
  __syncthreads();

  // ---- phase C: K = mf*32 + r; feature jarr = {mf, r/9, (r/3)%3, r%3} ----
  for (int idx = tid; idx < 1152; idx += 768) {   // 12 channels x 96 K
    int cq = idx / 96;
    int K  = idx - cq * 96;
    int mf = K >> 5, r = K & 31;
    if (r >= 27) continue;                        // zero-padded
    int jarr[4] = {mf, r / 9, (r / 3) % 3, r % 3};
    float acc = 0.f;
    for (int sel = 0; sel < 16; ++sel) {
      int kk = 0, ll = 0;
      float sg = 1.f;
#pragma unroll
      for (int q = 0; q < 4; ++q) {
        int t = (sel >> (3 - q)) & 1;
        kk |= t << (3 - q);
        int lb = (jarr[q] == 2) ? (1 - t) : t;
        ll |= lb << (3 - q);
        if (jarr[q] == 1 && t) sg = -sg;
      }
      acc += sg * ldsA[(cq * 16 + kk) * 16 + ll];
    }
    float T = acc * 0.0625f;
    _Float16 th = (_Float16)T;
    _Float16 tl = (_Float16)(T - (float)th);
    int L  = ((r >> 3) << 4) | cq;
    int jj = r & 7;
    Tws[((mf * 2 + 0) * 64 + L) * 8 + jj] = th;
    Tws[((mf * 2 + 1) * 64 + L) * 8 + jj] = tl;
  }
}

// ---------------------------------------------------------------------------
// qconv_main: block = 256 threads (4 waves, 256 rows), grid 2048.
// Per lane: 2x2 patch -> 4 sincos -> g123[27] (f1 (x) f2 (x) f3) + f0 triple
// -> f16 -> LDS (row stride 40 halves = 80 B, 16B-aligned; 20 KB/block ->
// 4+ blocks/CU). Per 16-row set t: 1 ds_read_b128 (g123 slice quad*8..+8,
// shared across mf) + 1 ds_read_b64 (f0) -> bf = f0[mf]*slice (packed f16)
// -> 6 chained mfma_f32_16x16x32_f16 over (mf, hi/lo); 4 independent acc
// chains; direct C-layout nontemporal float4 store.
// ---------------------------------------------------------------------------
__global__ __launch_bounds__(256, 4) void qconv_main(
    const float* __restrict__ x, const _Float16* __restrict__ T,
    float* __restrict__ out) {
  __shared__ _Float16 lds[256 * 40];
  const int tid  = threadIdx.x;
  const int wid  = tid >> 6;
  const int lane = tid & 63;
  const int quad = lane >> 4;
  const int n16  = lane & 15;
  const int r = blockIdx.x * 256 + tid;

  // 2x2 patch -> 4 angles (qubit0=lo.x, 1=hi.x, 2=lo.y, 3=hi.y)
  const int b  = r >> 10;
  const int h2 = (r >> 5) & 31;
  const int j  = r & 31;
  const float* xb = x + b * 4096 + h2 * 128 + j * 2;
  float2 lo = *(const float2*)(xb);
  float2 hi = *(const float2*)(xb + 64);
  float c0, s0, c1, s1, c2, s2, c3, s3;
  __sincosf(lo.x, &s0, &c0);
  __sincosf(hi.x, &s1, &c1);
  __sincosf(lo.y, &s2, &c2);
  __sincosf(hi.y, &s3, &c3);

  // g123[27] = f1 (x) f2 (x) f3;  f0 = {1, c0, s0}
  float f1a[3] = {1.f, c1, s1};
  float f23[9];
  {
    float f2a[3] = {1.f, c2, s2}, f3a[3] = {1.f, c3, s3};
#pragma unroll
    for (int a = 0; a < 9; ++a) f23[a] = f2a[a / 3] * f3a[a % 3];
  }
  __align__(16) _Float16 gh[32];
#pragma unroll
  for (int r1 = 0; r1 < 3; ++r1)
#pragma unroll
    for (int b9 = 0; b9 < 9; ++b9)
      gh[r1 * 9 + b9] = (_Float16)(f1a[r1] * f23[b9]);
#pragma unroll
  for (int e = 27; e < 32; ++e) gh[e] = (_Float16)0.f;

  {
    half8* dst = (half8*)&lds[tid * 40];
    dst[0] = *(const half8*)&gh[0];
    dst[1] = *(const half8*)&gh[8];
    dst[2] = *(const half8*)&gh[16];
    dst[3] = *(const half8*)&gh[24];
    half4 f0h = {(_Float16)1.f, (_Float16)c0, (_Float16)s0, (_Float16)0.f};
    *(half4*)&lds[tid * 40 + 32] = f0h;
  }
  __syncthreads();

  // A-fragments (T hi/lo per K-chunk)
  const half8* Tv = (const half8*)T;
  half8 afh[3], afl[3];
#pragma unroll
  for (int mf = 0; mf < 3; ++mf) {
    afh[mf] = Tv[(mf * 2 + 0) * 64 + lane];
    afl[mf] = Tv[(mf * 2 + 1) * 64 + lane];
  }

  // load all 4 sets' slices + f0 triples (wave-local rows)
  half8 slice[4];
  half4 f0v[4];
#pragma unroll
  for (int t = 0; t < 4; ++t) {
    const int row = wid * 64 + t * 16 + n16;
    slice[t] = *(const half8*)&lds[row * 40 + quad * 8];
    f0v[t]   = *(const half4*)&lds[row * 40 + 32];
  }

  float4v acc[4];
#pragma unroll
  for (int t = 0; t < 4; ++t) acc[t] = (float4v){0.f, 0.f, 0.f, 0.f};
#pragma unroll
  for (int mf = 0; mf < 3; ++mf) {
#pragma unroll
    for (int t = 0; t < 4; ++t) {
      _Float16 f0s = f0v[t][mf];
      half8 bf;
#pragma unroll
      for (int e = 0; e < 8; ++e) bf[e] = slice[t][e] * f0s;
      acc[t] = __builtin_amdgcn_mfma_f32_16x16x32_f16(afl[mf], bf, acc[t], 0, 0, 0);
      acc[t] = __builtin_amdgcn_mfma_f32_16x16x32_f16(afh[mf], bf, acc[t], 0, 0, 0);
    }
  }

  // C layout: col = n16 = data row, row = quad*4+v = channel (12 used)
  if (quad < 3) {
#pragma unroll
    for (int t = 0; t < 4; ++t) {
      int rowg = blockIdx.x * 256 + wid * 64 + t * 16 + n16;
      float4v ev = acc[t];
      __builtin_nontemporal_store(ev, (float4v*)(out + (size_t)rowg * 12 + quad * 4));
    }
  }
}

}  // namespace

extern "C" void kernel_launch(void* const* d_in, const int* in_sizes, int n_in,
                              void* d_out, int out_size, void* d_ws, size_t ws_size,
                              hipStream_t stream) {
  const float* x      = (const float*)d_in[0];
  const float* params = (const float*)d_in[1];
  float* out = (float*)d_out;
  _Float16* Tws = (_Float16*)d_ws;   // 3072 halves (6 KB) used

  GateList gl;
  build_gatelist(gl);                // deterministic every call (seed 1024)

  hipLaunchKernelGGL(build_T, dim3(1), dim3(768), 0, stream, params, Tws, gl);

  int nrows = in_sizes[0] / 4;       // 524288
  int grid  = nrows / 256;           // 2048 blocks
  hipLaunchKernelGGL(qconv_main, dim3(grid), dim3(256), 0, stream,
                     x, Tws, out);
}